// Round 6
// baseline (185.578 us; speedup 1.0000x reference)
//
#include <hip/hip_runtime.h>
#include <math.h>

// FreqPSR: patch-wise FFT phase/amplitude swap attack.
// out[0 .. 25165823]        = PhaseAttack     (128,64,3,32,32) f32
// out[25165824 .. 50331647] = AmplitudeAttack (128,64,3,32,32) f32
static constexpr int HALF_OUT = 128 * 64 * 3 * 32 * 32; // 25165824

typedef float floatx4 __attribute__((ext_vector_type(4)));

__device__ __forceinline__ float fsqrt(float x) { return __builtin_amdgcn_sqrtf(x); }
__device__ __forceinline__ float frcp(float x)  { return __builtin_amdgcn_rcpf(x); }

// Real-output IFFT2(4x4) of a Hermitian pre-scaled spectrum + |.| + plain store.
// Only zim[1,3,4..7,9,11,12..15] are read (Hermitian rows 0,2 need no imag parts).
__device__ __forceinline__ void ifft_real_store(const float zre[16], const float zim[16],
                                                float* __restrict__ obase) {
    float gr[4][4], gi1[4], gi3[4];
    // rows ku = 0, 2 : only real g needed
    #pragma unroll
    for (int rr = 0; rr < 2; ++rr) {
        const int ku = rr * 2, b0 = ku * 4;
        float t0r = zre[b0+0] + zre[b0+2];
        float t1r = zre[b0+0] - zre[b0+2];
        float t2r = zre[b0+1] + zre[b0+3];
        float t3i = zim[b0+1] - zim[b0+3];
        gr[ku][0] = t0r + t2r; gr[ku][2] = t0r - t2r;
        gr[ku][1] = t1r - t3i; gr[ku][3] = t1r + t3i;
    }
    // rows ku = 1, 3 : full complex
    #pragma unroll
    for (int rr = 0; rr < 2; ++rr) {
        const int ku = rr * 2 + 1, b0 = ku * 4;
        float* gi = (rr == 0) ? gi1 : gi3;   // compile-time resolved (unrolled)
        float t0r = zre[b0+0] + zre[b0+2], t0i = zim[b0+0] + zim[b0+2];
        float t1r = zre[b0+0] - zre[b0+2], t1i = zim[b0+0] - zim[b0+2];
        float t2r = zre[b0+1] + zre[b0+3], t2i = zim[b0+1] + zim[b0+3];
        float t3r = zre[b0+1] - zre[b0+3], t3i = zim[b0+1] - zim[b0+3];
        gr[ku][0] = t0r + t2r; gi[0] = t0i + t2i;
        gr[ku][2] = t0r - t2r; gi[2] = t0i - t2i;
        gr[ku][1] = t1r - t3i; gi[1] = t1i + t3r;
        gr[ku][3] = t1r + t3i; gi[3] = t1i - t3r;
    }
    float ov[4][4];
    #pragma unroll
    for (int v = 0; v < 4; ++v) {
        float a  = gr[0][v] + gr[2][v];
        float bq = gr[0][v] - gr[2][v];
        float cq = gr[1][v] + gr[3][v];
        float e  = gi3[v] - gi1[v];
        ov[0][v] = fabsf(a + cq);
        ov[2][v] = fabsf(a - cq);
        ov[1][v] = fabsf(bq + e);
        ov[3][v] = fabsf(bq - e);
    }
    #pragma unroll
    for (int u = 0; u < 4; ++u) {
        floatx4 w4 = { ov[u][0], ov[u][1], ov[u][2], ov[u][3] };
        *reinterpret_cast<floatx4*>(obase + u * 32) = w4;   // plain store (A/B vs nt)
    }
}

__global__ __launch_bounds__(256, 4) void freqpsr_kernel(
    const float* __restrict__ adv,
    const float* __restrict__ cle,
    float* __restrict__ out)
{
    // Bin-major [k][p] layout: lane=p -> stride 4B/8B, conflict-free (2 lanes/bank).
    __shared__ float2 sA   [16][64];  // adv spectrum (scratch, consumed by stage 2)
    __shared__ float2 sC   [16][64];  // clean spectrum * 1/16 (pre-scaled for IFFT)
    __shared__ float  sCamp[16][64];  // |C|      (unscaled, for equality compare)
    __shared__ float  sCpha[16][64];  // angle(C) (for equality compare)
    __shared__ float2 sZA  [16][64];  // (|C| * unit(A)) * 1/16
    __shared__ float  sRatB[16][64];  // |A| / |C| (unitless ratio)

    const int blk  = blockIdx.x;      // 1536 blocks = 128 b * 3 c * 2 type * 2 ah
    const int ah   = blk & 1;         // attack half: attacks [ah*32, ah*32+32)
    const int type = (blk >> 1) & 1;  // 0 = phase attack, 1 = amplitude attack
    const int bc   = blk >> 2;
    const int b    = bc / 3;
    const int c    = bc % 3;
    const int tid  = threadIdx.x;

    // ---------------- Stage 1: FFT2 of every 4x4 patch (clean & adv) ----------------
    if (tid < 128) {
        const int p   = tid & 63;     // patch index (py*8+px)
        const int img = tid >> 6;     // 0 = clean, 1 = adv
        const float* src = (img ? adv : cle) + ((size_t)b * 3 + c) * 1024;
        const int py = p >> 3, px = p & 7;

        float x[4][4];
        #pragma unroll
        for (int u = 0; u < 4; ++u) {
            float4 r4 = *reinterpret_cast<const float4*>(src + (py * 4 + u) * 32 + px * 4);
            x[u][0] = r4.x; x[u][1] = r4.y; x[u][2] = r4.z; x[u][3] = r4.w;
        }
        float wr[4][4], wi[4][4]; // [u][kv]
        #pragma unroll
        for (int u = 0; u < 4; ++u) {
            float t0 = x[u][0] + x[u][2], t1 = x[u][0] - x[u][2];
            float t2 = x[u][1] + x[u][3], t3 = x[u][1] - x[u][3];
            wr[u][0] = t0 + t2; wi[u][0] = 0.0f;
            wr[u][2] = t0 - t2; wi[u][2] = 0.0f;
            wr[u][1] = t1;      wi[u][1] = -t3;
            wr[u][3] = t1;      wi[u][3] =  t3;
        }
        float zr[4][4], zi[4][4]; // [ku][kv]
        #pragma unroll
        for (int kv = 0; kv < 4; ++kv) {
            float t0r = wr[0][kv] + wr[2][kv], t0i = wi[0][kv] + wi[2][kv];
            float t1r = wr[0][kv] - wr[2][kv], t1i = wi[0][kv] - wi[2][kv];
            float t2r = wr[1][kv] + wr[3][kv], t2i = wi[1][kv] + wi[3][kv];
            float t3r = wr[1][kv] - wr[3][kv], t3i = wi[1][kv] - wi[3][kv];
            zr[0][kv] = t0r + t2r; zi[0][kv] = t0i + t2i;
            zr[2][kv] = t0r - t2r; zi[2][kv] = t0i - t2i;
            zr[1][kv] = t1r + t3i; zi[1][kv] = t1i - t3r;
            zr[3][kv] = t1r - t3i; zi[3][kv] = t1i + t3r;
        }
        if (img == 0) {
            #pragma unroll
            for (int k = 0; k < 16; ++k) {
                float re = zr[k >> 2][k & 3], im = zi[k >> 2][k & 3];
                sC[k][p]    = make_float2(re * 0.0625f, im * 0.0625f);
                sCamp[k][p] = fsqrt(re * re + im * im);
                sCpha[k][p] = atan2f(im, re);
            }
        } else {
            #pragma unroll
            for (int k = 0; k < 16; ++k)
                sA[k][p] = make_float2(zr[k >> 2][k & 3], zi[k >> 2][k & 3]);
        }
    }
    __syncthreads();

    // ---------------- Stage 2: derived per-(patch,bin) arrays ----------------
    for (int item = tid; item < 1024; item += 256) {
        const int k = item >> 6, p = item & 63;
        float2 a = sA[k][p];
        float aamp = fsqrt(a.x * a.x + a.y * a.y);
        float camp = sCamp[k][p];
        float2 za;
        if (aamp > 0.0f) { float s = camp * 0.0625f * frcp(aamp); za = make_float2(s * a.x, s * a.y); }
        else             { za = make_float2(camp * 0.0625f, 0.0f); } // exp(i*angle(0)) == 1
        sZA[k][p]   = za;
        sRatB[k][p] = (camp > 0.0f) ? (aamp * frcp(camp)) : 0.0f;
    }
    __syncthreads();

    // ---------------- Stage 3: 32 attacks of ONE type (8 per wave) ----------------
    const int wave = tid >> 6;
    const int p    = tid & 63;
    const int py   = p >> 3, px = p & 7;

    float ccr[16], cci[16];
    #pragma unroll
    for (int k = 0; k < 16; ++k) { float2 cc = sC[k][p]; ccr[k] = cc.x; cci[k] = cc.y; }

    const int i0 = ah * 32 + wave * 8;   // this wave's first attack index
    float* const obase0 = out + (size_t)(type ? HALF_OUT : 0)
                              + ((((size_t)b * 64) * 3 + c) << 10)
                              + py * 128 + px * 4;

    if (type == 0) { // ---------- phase attack: Z = (cpha==att) ? ZA : C ----------
        float cphar[16], zar[16], zai[16];
        #pragma unroll
        for (int k = 0; k < 16; ++k) {
            cphar[k] = sCpha[k][p];
            float2 za = sZA[k][p]; zar[k] = za.x; zai[k] = za.y;
        }
        for (int j = 0; j < 8; ++j) {
            const int i = i0 + j;
            float zre[16], zim[16];
            #pragma unroll
            for (int k = 0; k < 16; ++k) {
                float att = sCpha[k][i];           // LDS broadcast
                bool sw = (cphar[k] == att);
                zre[k] = sw ? zar[k] : ccr[k];
                if (k != 0 && k != 2 && k != 8 && k != 10)
                    zim[k] = sw ? zai[k] : cci[k];
            }
            zim[0] = zim[2] = zim[8] = zim[10] = 0.0f; // dead (Hermitian rows)
            ifft_real_store(zre, zim, obase0 + (size_t)i * 3072);
        }
    } else { // ---------- amplitude attack: Z = ((camp==att) ? ratB : 1) * C ----------
        float campr[16], ratr[16];
        #pragma unroll
        for (int k = 0; k < 16; ++k) { campr[k] = sCamp[k][p]; ratr[k] = sRatB[k][p]; }
        for (int j = 0; j < 8; ++j) {
            const int i = i0 + j;
            float zre[16], zim[16];
            #pragma unroll
            for (int k = 0; k < 16; ++k) {
                float att = sCamp[k][i];           // LDS broadcast
                float r = (campr[k] == att) ? ratr[k] : 1.0f;
                zre[k] = r * ccr[k];
                if (k != 0 && k != 2 && k != 8 && k != 10)
                    zim[k] = r * cci[k];
            }
            zim[0] = zim[2] = zim[8] = zim[10] = 0.0f;
            ifft_real_store(zre, zim, obase0 + (size_t)i * 3072);
        }
    }
}

extern "C" void kernel_launch(void* const* d_in, const int* in_sizes, int n_in,
                              void* d_out, int out_size, void* d_ws, size_t ws_size,
                              hipStream_t stream) {
    const float* adv = (const float*)d_in[0];   // adver_image (128,3,32,32)
    const float* cle = (const float*)d_in[1];   // clean_image (128,3,32,32)
    float* out = (float*)d_out;                 // 2 * 128*64*3*32*32 f32
    (void)in_sizes; (void)n_in; (void)out_size; (void)d_ws; (void)ws_size;

    dim3 grid(128 * 3 * 2 * 2); // (b, c, type, attack-half)
    dim3 block(256);
    freqpsr_kernel<<<grid, block, 0, stream>>>(adv, cle, out);
}

// Round 7
// 38.209 us; speedup vs baseline: 4.8569x; 4.8569x over previous
//
#include <hip/hip_runtime.h>
#include <math.h>

// FreqPSR: patch-wise FFT phase/amplitude swap attack.
// out[0 .. 25165823]        = PhaseAttack     (128,64,3,32,32) f32
// out[25165824 .. 50331647] = AmplitudeAttack (128,64,3,32,32) f32
static constexpr int HALF_OUT = 128 * 64 * 3 * 32 * 32; // 25165824

typedef float floatx4 __attribute__((ext_vector_type(4)));

__device__ __forceinline__ float fsqrt(float x) { return __builtin_amdgcn_sqrtf(x); }
__device__ __forceinline__ float frcp(float x)  { return __builtin_amdgcn_rcpf(x); }

// Real-output IFFT2(4x4) of a Hermitian pre-scaled spectrum + |.| + plain store.
// Only zim[1,3,4..7,9,11,12..15] are read (Hermitian rows 0,2 need no imag parts).
__device__ __forceinline__ void ifft_real_store(const float zre[16], const float zim[16],
                                                float* __restrict__ obase) {
    float gr[4][4], gi1[4], gi3[4];
    // rows ku = 0, 2 : only real g needed
    #pragma unroll
    for (int rr = 0; rr < 2; ++rr) {
        const int ku = rr * 2, b0 = ku * 4;
        float t0r = zre[b0+0] + zre[b0+2];
        float t1r = zre[b0+0] - zre[b0+2];
        float t2r = zre[b0+1] + zre[b0+3];
        float t3i = zim[b0+1] - zim[b0+3];
        gr[ku][0] = t0r + t2r; gr[ku][2] = t0r - t2r;
        gr[ku][1] = t1r - t3i; gr[ku][3] = t1r + t3i;
    }
    // rows ku = 1, 3 : full complex
    #pragma unroll
    for (int rr = 0; rr < 2; ++rr) {
        const int ku = rr * 2 + 1, b0 = ku * 4;
        float* gi = (rr == 0) ? gi1 : gi3;   // compile-time resolved (unrolled)
        float t0r = zre[b0+0] + zre[b0+2], t0i = zim[b0+0] + zim[b0+2];
        float t1r = zre[b0+0] - zre[b0+2], t1i = zim[b0+0] - zim[b0+2];
        float t2r = zre[b0+1] + zre[b0+3], t2i = zim[b0+1] + zim[b0+3];
        float t3r = zre[b0+1] - zre[b0+3], t3i = zim[b0+1] - zim[b0+3];
        gr[ku][0] = t0r + t2r; gi[0] = t0i + t2i;
        gr[ku][2] = t0r - t2r; gi[2] = t0i - t2i;
        gr[ku][1] = t1r - t3i; gi[1] = t1i + t3r;
        gr[ku][3] = t1r + t3i; gi[3] = t1i - t3r;
    }
    float ov[4][4];
    #pragma unroll
    for (int v = 0; v < 4; ++v) {
        float a  = gr[0][v] + gr[2][v];
        float bq = gr[0][v] - gr[2][v];
        float cq = gr[1][v] + gr[3][v];
        float e  = gi3[v] - gi1[v];
        ov[0][v] = fabsf(a + cq);
        ov[2][v] = fabsf(a - cq);
        ov[1][v] = fabsf(bq + e);
        ov[3][v] = fabsf(bq - e);
    }
    #pragma unroll
    for (int u = 0; u < 4; ++u) {
        floatx4 w4 = { ov[u][0], ov[u][1], ov[u][2], ov[u][3] };
        *reinterpret_cast<floatx4*>(obase + u * 32) = w4;   // plain store (A/B vs R5's nt)
    }
}

__global__ __launch_bounds__(256, 3) void freqpsr_kernel(
    const float* __restrict__ adv,
    const float* __restrict__ cle,
    float* __restrict__ out)
{
    // Bin-major [k][p] layout: lane=p -> stride 4B/8B, conflict-free (2 lanes/bank).
    __shared__ float2 sA   [16][64];  // adv spectrum (scratch, consumed by stage 2)
    __shared__ float2 sC   [16][64];  // clean spectrum * 1/16 (pre-scaled for IFFT)
    __shared__ float  sCamp[16][64];  // |C|      (unscaled, for equality compare)
    __shared__ float  sCpha[16][64];  // angle(C) (for equality compare)
    __shared__ float2 sZA  [16][64];  // (|C| * unit(A)) * 1/16
    __shared__ float  sRatB[16][64];  // |A| / |C| (unitless ratio)

    const int blk  = blockIdx.x;      // 768 blocks = 128 b * 3 c * 2 type
    const int type = blk & 1;         // 0 = phase attack, 1 = amplitude attack
    const int bc   = blk >> 1;
    const int b    = bc / 3;
    const int c    = bc % 3;
    const int tid  = threadIdx.x;

    // ---------------- Stage 1: FFT2 of every 4x4 patch (clean & adv) ----------------
    if (tid < 128) {
        const int p   = tid & 63;     // patch index (py*8+px)
        const int img = tid >> 6;     // 0 = clean, 1 = adv
        const float* src = (img ? adv : cle) + ((size_t)b * 3 + c) * 1024;
        const int py = p >> 3, px = p & 7;

        float x[4][4];
        #pragma unroll
        for (int u = 0; u < 4; ++u) {
            float4 r4 = *reinterpret_cast<const float4*>(src + (py * 4 + u) * 32 + px * 4);
            x[u][0] = r4.x; x[u][1] = r4.y; x[u][2] = r4.z; x[u][3] = r4.w;
        }
        float wr[4][4], wi[4][4]; // [u][kv]
        #pragma unroll
        for (int u = 0; u < 4; ++u) {
            float t0 = x[u][0] + x[u][2], t1 = x[u][0] - x[u][2];
            float t2 = x[u][1] + x[u][3], t3 = x[u][1] - x[u][3];
            wr[u][0] = t0 + t2; wi[u][0] = 0.0f;
            wr[u][2] = t0 - t2; wi[u][2] = 0.0f;
            wr[u][1] = t1;      wi[u][1] = -t3;
            wr[u][3] = t1;      wi[u][3] =  t3;
        }
        float zr[4][4], zi[4][4]; // [ku][kv]
        #pragma unroll
        for (int kv = 0; kv < 4; ++kv) {
            float t0r = wr[0][kv] + wr[2][kv], t0i = wi[0][kv] + wi[2][kv];
            float t1r = wr[0][kv] - wr[2][kv], t1i = wi[0][kv] - wi[2][kv];
            float t2r = wr[1][kv] + wr[3][kv], t2i = wi[1][kv] + wi[3][kv];
            float t3r = wr[1][kv] - wr[3][kv], t3i = wi[1][kv] - wi[3][kv];
            zr[0][kv] = t0r + t2r; zi[0][kv] = t0i + t2i;
            zr[2][kv] = t0r - t2r; zi[2][kv] = t0i - t2i;
            zr[1][kv] = t1r + t3i; zi[1][kv] = t1i - t3r;
            zr[3][kv] = t1r - t3i; zi[3][kv] = t1i + t3r;
        }
        if (img == 0) {
            #pragma unroll
            for (int k = 0; k < 16; ++k) {
                float re = zr[k >> 2][k & 3], im = zi[k >> 2][k & 3];
                sC[k][p]    = make_float2(re * 0.0625f, im * 0.0625f);
                sCamp[k][p] = fsqrt(re * re + im * im);
                sCpha[k][p] = atan2f(im, re);
            }
        } else {
            #pragma unroll
            for (int k = 0; k < 16; ++k)
                sA[k][p] = make_float2(zr[k >> 2][k & 3], zi[k >> 2][k & 3]);
        }
    }
    __syncthreads();

    // ---------------- Stage 2: derived per-(patch,bin) arrays ----------------
    for (int item = tid; item < 1024; item += 256) {
        const int k = item >> 6, p = item & 63;
        float2 a = sA[k][p];
        float aamp = fsqrt(a.x * a.x + a.y * a.y);
        float camp = sCamp[k][p];
        float2 za;
        if (aamp > 0.0f) { float s = camp * 0.0625f * frcp(aamp); za = make_float2(s * a.x, s * a.y); }
        else             { za = make_float2(camp * 0.0625f, 0.0f); } // exp(i*angle(0)) == 1
        sZA[k][p]   = za;
        sRatB[k][p] = (camp > 0.0f) ? (aamp * frcp(camp)) : 0.0f;
    }
    __syncthreads();

    // ---------------- Stage 3: this block does all 64 attacks of ONE type ----------
    const int wave = tid >> 6;
    const int p    = tid & 63;
    const int py   = p >> 3, px = p & 7;

    float ccr[16], cci[16];
    #pragma unroll
    for (int k = 0; k < 16; ++k) { float2 cc = sC[k][p]; ccr[k] = cc.x; cci[k] = cc.y; }

    float* const obase0 = out + (size_t)(type ? HALF_OUT : 0)
                              + ((((size_t)b * 64) * 3 + c) << 10)
                              + py * 128 + px * 4;

    if (type == 0) { // ---------- phase attack: Z = (cpha==att) ? ZA : C ----------
        float cphar[16], zar[16], zai[16];
        #pragma unroll
        for (int k = 0; k < 16; ++k) {
            cphar[k] = sCpha[k][p];
            float2 za = sZA[k][p]; zar[k] = za.x; zai[k] = za.y;
        }
        for (int j = 0; j < 16; ++j) {
            const int i = wave * 16 + j;           // attack index 0..63
            float zre[16], zim[16];
            #pragma unroll
            for (int k = 0; k < 16; ++k) {
                float att = sCpha[k][i];           // LDS broadcast
                bool sw = (cphar[k] == att);
                zre[k] = sw ? zar[k] : ccr[k];
                if (k != 0 && k != 2 && k != 8 && k != 10)
                    zim[k] = sw ? zai[k] : cci[k];
            }
            zim[0] = zim[2] = zim[8] = zim[10] = 0.0f; // dead (Hermitian rows)
            ifft_real_store(zre, zim, obase0 + (size_t)i * 3072);
        }
    } else { // ---------- amplitude attack: Z = ((camp==att) ? ratB : 1) * C ----------
        float campr[16], ratr[16];
        #pragma unroll
        for (int k = 0; k < 16; ++k) { campr[k] = sCamp[k][p]; ratr[k] = sRatB[k][p]; }
        for (int j = 0; j < 16; ++j) {
            const int i = wave * 16 + j;
            float zre[16], zim[16];
            #pragma unroll
            for (int k = 0; k < 16; ++k) {
                float att = sCamp[k][i];           // LDS broadcast
                float r = (campr[k] == att) ? ratr[k] : 1.0f;
                zre[k] = r * ccr[k];
                if (k != 0 && k != 2 && k != 8 && k != 10)
                    zim[k] = r * cci[k];
            }
            zim[0] = zim[2] = zim[8] = zim[10] = 0.0f;
            ifft_real_store(zre, zim, obase0 + (size_t)i * 3072);
        }
    }
}

extern "C" void kernel_launch(void* const* d_in, const int* in_sizes, int n_in,
                              void* d_out, int out_size, void* d_ws, size_t ws_size,
                              hipStream_t stream) {
    const float* adv = (const float*)d_in[0];   // adver_image (128,3,32,32)
    const float* cle = (const float*)d_in[1];   // clean_image (128,3,32,32)
    float* out = (float*)d_out;                 // 2 * 128*64*3*32*32 f32
    (void)in_sizes; (void)n_in; (void)out_size; (void)d_ws; (void)ws_size;

    dim3 grid(128 * 3 * 2); // (b, c, type)
    dim3 block(256);
    freqpsr_kernel<<<grid, block, 0, stream>>>(adv, cle, out);
}

// Round 8
// 37.656 us; speedup vs baseline: 4.9283x; 1.0147x over previous
//
#include <hip/hip_runtime.h>
#include <math.h>

// FreqPSR: patch-wise FFT phase/amplitude swap attack.
// out[0 .. 25165823]        = PhaseAttack     (128,64,3,32,32) f32
// out[25165824 .. 50331647] = AmplitudeAttack (128,64,3,32,32) f32
static constexpr int HALF_OUT = 128 * 64 * 3 * 32 * 32; // 25165824

typedef float floatx4 __attribute__((ext_vector_type(4)));

__device__ __forceinline__ float fsqrt(float x) { return __builtin_amdgcn_sqrtf(x); }
__device__ __forceinline__ float frcp(float x)  { return __builtin_amdgcn_rcpf(x); }

// float32 pi, bit-identical to atan2f(+0.0f, negative) == 0x40490FDB
#define PI_F 3.14159274101257324f

// Real-output IFFT2(4x4) of a Hermitian pre-scaled spectrum + |.| + plain store.
// Only zim[1,3,4..7,9,11,12..15] are read (Hermitian rows 0,2 need no imag parts).
__device__ __forceinline__ void ifft_real_store(const float zre[16], const float zim[16],
                                                float* __restrict__ obase) {
    float gr[4][4], gi1[4], gi3[4];
    // rows ku = 0, 2 : only real g needed
    #pragma unroll
    for (int rr = 0; rr < 2; ++rr) {
        const int ku = rr * 2, b0 = ku * 4;
        float t0r = zre[b0+0] + zre[b0+2];
        float t1r = zre[b0+0] - zre[b0+2];
        float t2r = zre[b0+1] + zre[b0+3];
        float t3i = zim[b0+1] - zim[b0+3];
        gr[ku][0] = t0r + t2r; gr[ku][2] = t0r - t2r;
        gr[ku][1] = t1r - t3i; gr[ku][3] = t1r + t3i;
    }
    // rows ku = 1, 3 : full complex
    #pragma unroll
    for (int rr = 0; rr < 2; ++rr) {
        const int ku = rr * 2 + 1, b0 = ku * 4;
        float* gi = (rr == 0) ? gi1 : gi3;   // compile-time resolved (unrolled)
        float t0r = zre[b0+0] + zre[b0+2], t0i = zim[b0+0] + zim[b0+2];
        float t1r = zre[b0+0] - zre[b0+2], t1i = zim[b0+0] - zim[b0+2];
        float t2r = zre[b0+1] + zre[b0+3], t2i = zim[b0+1] + zim[b0+3];
        float t3r = zre[b0+1] - zre[b0+3], t3i = zim[b0+1] - zim[b0+3];
        gr[ku][0] = t0r + t2r; gi[0] = t0i + t2i;
        gr[ku][2] = t0r - t2r; gi[2] = t0i - t2i;
        gr[ku][1] = t1r - t3i; gi[1] = t1i + t3r;
        gr[ku][3] = t1r + t3i; gi[3] = t1i - t3r;
    }
    float ov[4][4];
    #pragma unroll
    for (int v = 0; v < 4; ++v) {
        float a  = gr[0][v] + gr[2][v];
        float bq = gr[0][v] - gr[2][v];
        float cq = gr[1][v] + gr[3][v];
        float e  = gi3[v] - gi1[v];
        ov[0][v] = fabsf(a + cq);
        ov[2][v] = fabsf(a - cq);
        ov[1][v] = fabsf(bq + e);
        ov[3][v] = fabsf(bq - e);
    }
    #pragma unroll
    for (int u = 0; u < 4; ++u) {
        floatx4 w4 = { ov[u][0], ov[u][1], ov[u][2], ov[u][3] };
        *reinterpret_cast<floatx4*>(obase + u * 32) = w4;   // plain store (R7: beats nt)
    }
}

__global__ __launch_bounds__(256, 3) void freqpsr_kernel(
    const float* __restrict__ adv,
    const float* __restrict__ cle,
    float* __restrict__ out)
{
    // Bin-major [k][p]: lane=p -> stride 4B/8B, conflict-free.
    __shared__ float2 sA    [16][64]; // adv spectrum (raw, consumed by stage 2)
    __shared__ float2 sC    [16][64]; // clean spectrum: raw after st1, *1/16 after st2
    __shared__ float  sCamp [16][64]; // |C| (unscaled, per-lane compare operand)
    __shared__ float  sCpha [16][64]; // angle(C) (per-lane compare operand)
    __shared__ float2 sZA   [16][64]; // (|C| * unit(A)) * 1/16
    __shared__ float  sRatB [16][64]; // |A| / |C|
    __shared__ float  sCphaT[64][16]; // transposed copy: attacker row broadcast (b128)
    __shared__ float  sCampT[64][16]; // transposed copy: attacker row broadcast (b128)

    const int blk  = blockIdx.x;      // 768 blocks = 128 b * 3 c * 2 type
    const int type = blk & 1;         // 0 = phase attack, 1 = amplitude attack
    const int bc   = blk >> 1;
    const int b    = bc / 3;
    const int c    = bc % 3;
    const int tid  = threadIdx.x;

    // ---------------- Stage 1: FFT2 of every 4x4 patch (raw spectra only) ----------
    if (tid < 128) {
        const int p   = tid & 63;     // patch index (py*8+px)
        const int img = tid >> 6;     // 0 = clean, 1 = adv
        const float* src = (img ? adv : cle) + ((size_t)b * 3 + c) * 1024;
        const int py = p >> 3, px = p & 7;

        float x[4][4];
        #pragma unroll
        for (int u = 0; u < 4; ++u) {
            float4 r4 = *reinterpret_cast<const float4*>(src + (py * 4 + u) * 32 + px * 4);
            x[u][0] = r4.x; x[u][1] = r4.y; x[u][2] = r4.z; x[u][3] = r4.w;
        }
        float wr[4][4], wi[4][4]; // [u][kv]
        #pragma unroll
        for (int u = 0; u < 4; ++u) {
            float t0 = x[u][0] + x[u][2], t1 = x[u][0] - x[u][2];
            float t2 = x[u][1] + x[u][3], t3 = x[u][1] - x[u][3];
            wr[u][0] = t0 + t2; wi[u][0] = 0.0f;
            wr[u][2] = t0 - t2; wi[u][2] = 0.0f;
            wr[u][1] = t1;      wi[u][1] = -t3;
            wr[u][3] = t1;      wi[u][3] =  t3;
        }
        float zr[4][4], zi[4][4]; // [ku][kv]
        #pragma unroll
        for (int kv = 0; kv < 4; ++kv) {
            float t0r = wr[0][kv] + wr[2][kv], t0i = wi[0][kv] + wi[2][kv];
            float t1r = wr[0][kv] - wr[2][kv], t1i = wi[0][kv] - wi[2][kv];
            float t2r = wr[1][kv] + wr[3][kv], t2i = wi[1][kv] + wi[3][kv];
            float t3r = wr[1][kv] - wr[3][kv], t3i = wi[1][kv] - wi[3][kv];
            zr[0][kv] = t0r + t2r; zi[0][kv] = t0i + t2i;
            zr[2][kv] = t0r - t2r; zi[2][kv] = t0i - t2i;
            zr[1][kv] = t1r + t3i; zi[1][kv] = t1i - t3r;
            zr[3][kv] = t1r - t3i; zi[3][kv] = t1i + t3r;
        }
        if (img == 0) {
            #pragma unroll
            for (int k = 0; k < 16; ++k)
                sC[k][p] = make_float2(zr[k >> 2][k & 3], zi[k >> 2][k & 3]);
        } else {
            #pragma unroll
            for (int k = 0; k < 16; ++k)
                sA[k][p] = make_float2(zr[k >> 2][k & 3], zi[k >> 2][k & 3]);
        }
    }
    __syncthreads();

    // ------- Stage 2: derived per-(patch,bin) arrays, spread over ALL 256 threads ----
    {
        const int p2 = tid >> 2;           // patch 0..63
        const int k4 = (tid & 3) * 4;      // 4 consecutive bins
        float phaq[4], ampq[4];
        #pragma unroll
        for (int n = 0; n < 4; ++n) {
            const int k = k4 + n;
            float2 cc = sC[k][p2];
            float2 a  = sA[k][p2];
            float camp = fsqrt(cc.x * cc.x + cc.y * cc.y);
            // bins (ku,kv) in {0,2}^2 have exactly +0 imag -> atan2f(+0,re) is 0 or pi
            bool realbin = (k == 0) | (k == 2) | (k == 8) | (k == 10);
            float cpha = realbin ? (cc.x < 0.0f ? PI_F : 0.0f) : atan2f(cc.y, cc.x);
            float aamp = fsqrt(a.x * a.x + a.y * a.y);
            float2 za;
            if (aamp > 0.0f) { float s = camp * 0.0625f * frcp(aamp); za = make_float2(s * a.x, s * a.y); }
            else             { za = make_float2(camp * 0.0625f, 0.0f); }
            sCamp[k][p2] = camp;
            sCpha[k][p2] = cpha;
            sZA[k][p2]   = za;
            sRatB[k][p2] = (camp > 0.0f) ? (aamp * frcp(camp)) : 0.0f;
            sC[k][p2]    = make_float2(cc.x * 0.0625f, cc.y * 0.0625f); // in-place rescale
            phaq[n] = cpha; ampq[n] = camp;
        }
        // transposed copies for broadcast reads (16B contiguous per thread)
        *reinterpret_cast<floatx4*>(&sCphaT[p2][k4]) = floatx4{ phaq[0], phaq[1], phaq[2], phaq[3] };
        *reinterpret_cast<floatx4*>(&sCampT[p2][k4]) = floatx4{ ampq[0], ampq[1], ampq[2], ampq[3] };
    }
    __syncthreads();

    // ---------------- Stage 3: this block does all 64 attacks of ONE type ----------
    const int wave = tid >> 6;
    const int p    = tid & 63;
    const int py   = p >> 3, px = p & 7;

    float ccr[16], cci[16];
    #pragma unroll
    for (int k = 0; k < 16; ++k) { float2 cc = sC[k][p]; ccr[k] = cc.x; cci[k] = cc.y; }

    float* const obase0 = out + (size_t)(type ? HALF_OUT : 0)
                              + ((((size_t)b * 64) * 3 + c) << 10)
                              + py * 128 + px * 4;

    if (type == 0) { // ---------- phase attack: Z = (cpha==att) ? ZA : C ----------
        float cphar[16], zar[16], zai[16];
        #pragma unroll
        for (int k = 0; k < 16; ++k) {
            cphar[k] = sCpha[k][p];
            float2 za = sZA[k][p]; zar[k] = za.x; zai[k] = za.y;
        }
        for (int j = 0; j < 16; ++j) {
            const int i = wave * 16 + j;           // attack index 0..63
            // attacker's 16 phases: 4 uniform-address b128 broadcasts
            const floatx4* prow = reinterpret_cast<const floatx4*>(&sCphaT[i][0]);
            floatx4 a0 = prow[0], a1 = prow[1], a2 = prow[2], a3 = prow[3];
            float att[16];
            #pragma unroll
            for (int n = 0; n < 4; ++n) { att[n] = a0[n]; att[4+n] = a1[n]; att[8+n] = a2[n]; att[12+n] = a3[n]; }
            float zre[16], zim[16];
            #pragma unroll
            for (int k = 0; k < 16; ++k) {
                bool sw = (cphar[k] == att[k]);
                zre[k] = sw ? zar[k] : ccr[k];
                if (k != 0 && k != 2 && k != 8 && k != 10)
                    zim[k] = sw ? zai[k] : cci[k];
            }
            zim[0] = zim[2] = zim[8] = zim[10] = 0.0f; // dead (Hermitian rows)
            ifft_real_store(zre, zim, obase0 + (size_t)i * 3072);
        }
    } else { // ---------- amplitude attack: Z = ((camp==att) ? ratB : 1) * C ----------
        float campr[16], ratr[16];
        #pragma unroll
        for (int k = 0; k < 16; ++k) { campr[k] = sCamp[k][p]; ratr[k] = sRatB[k][p]; }
        for (int j = 0; j < 16; ++j) {
            const int i = wave * 16 + j;
            const floatx4* prow = reinterpret_cast<const floatx4*>(&sCampT[i][0]);
            floatx4 a0 = prow[0], a1 = prow[1], a2 = prow[2], a3 = prow[3];
            float att[16];
            #pragma unroll
            for (int n = 0; n < 4; ++n) { att[n] = a0[n]; att[4+n] = a1[n]; att[8+n] = a2[n]; att[12+n] = a3[n]; }
            float zre[16], zim[16];
            #pragma unroll
            for (int k = 0; k < 16; ++k) {
                float r = (campr[k] == att[k]) ? ratr[k] : 1.0f;
                zre[k] = r * ccr[k];
                if (k != 0 && k != 2 && k != 8 && k != 10)
                    zim[k] = r * cci[k];
            }
            zim[0] = zim[2] = zim[8] = zim[10] = 0.0f;
            ifft_real_store(zre, zim, obase0 + (size_t)i * 3072);
        }
    }
}

extern "C" void kernel_launch(void* const* d_in, const int* in_sizes, int n_in,
                              void* d_out, int out_size, void* d_ws, size_t ws_size,
                              hipStream_t stream) {
    const float* adv = (const float*)d_in[0];   // adver_image (128,3,32,32)
    const float* cle = (const float*)d_in[1];   // clean_image (128,3,32,32)
    float* out = (float*)d_out;                 // 2 * 128*64*3*32*32 f32
    (void)in_sizes; (void)n_in; (void)out_size; (void)d_ws; (void)ws_size;

    dim3 grid(128 * 3 * 2); // (b, c, type)
    dim3 block(256);
    freqpsr_kernel<<<grid, block, 0, stream>>>(adv, cle, out);
}